// Round 9
// baseline (448.507 us; speedup 1.0000x reference)
//
#include <hip/hip_runtime.h>
#include <hip/hip_bf16.h>

#define NNODES 131072
#define NEDGES 2097152
#define NB     128
#define NPG    1024   // nodes per graph
#define EPG    16384  // edges per graph

// ws layout in 4-byte units (fallback path needs deg/cnt/rowstart/csr).
#define OFF_DEG      0                                   // 2*NNODES floats
#define OFF_POOLED   (OFF_DEG + 2*NNODES)                // 2*NB*64
#define OFF_WT       (OFF_POOLED + 2*NB*64)              // 96 KB wfrag
#define OFF_H        (OFF_WT + 6*4096)                   // 2*NNODES*64 ushort (slot sized f32)
#define OFF_CNT      (OFF_H + (size_t)2*NNODES*64)       // 2*NNODES ints
#define OFF_ROWSTART (OFF_CNT + 2*NNODES)                // 2*NNODES ints
#define OFF_CURSOR   (OFF_ROWSTART + 2*NNODES)           // 2*NNODES ints (layout keep)
#define OFF_CSR      (OFF_CURSOR + 2*NNODES)             // 2*NEDGES float2
#define WS_NEEDED    ((OFF_CSR + (size_t)4*NEDGES) * 4)

#define FUSE_LDS 145408   // 128K scsr + 4K sdeg + 4K scnt + 4K scur + 2K scan/red

typedef __attribute__((ext_vector_type(8))) short bfrag;
typedef __attribute__((ext_vector_type(4))) float f32x4;

__device__ __forceinline__ unsigned short f2bf(float v) {
    unsigned int u = __float_as_uint(v);
    unsigned int r = (u + 0x7fffu + ((u >> 16) & 1u)) >> 16;
    return (unsigned short)r;
}
__device__ __forceinline__ float bf2f(unsigned short s) {
    return __uint_as_float(((unsigned int)s) << 16);
}

// ---------------- pack six 64x64 weights into split-bf16 MFMA B-fragments.
// k-convention must equal the A-side assembly (contiguous-8):
//   col f = ft*16 + (lane&15);   k = kt*32 + (lane>>4)*8 + i
__global__ void wprep(const float* __restrict__ w0, const float* __restrict__ w1,
                      const float* __restrict__ w2, const float* __restrict__ w3,
                      const float* __restrict__ w4, const float* __restrict__ w5,
                      unsigned short* __restrict__ wf) {
    int m = blockIdx.x;
    const float* w = (m == 0) ? w0 : (m == 1) ? w1 : (m == 2) ? w2
                   : (m == 3) ? w3 : (m == 4) ? w4 : w5;
    for (int idx = threadIdx.x; idx < 4096; idx += blockDim.x) {
        int ft   = idx >> 10;
        int kt   = (idx >> 9) & 1;
        int lane = (idx >> 3) & 63;
        int i    = idx & 7;
        int f = ft * 16 + (lane & 15);
        int k = kt * 32 + ((lane >> 4) << 3) + i;
        float v = w[k * 64 + f];
        unsigned short hi = f2bf(v);
        unsigned short lo = f2bf(v - bf2f(hi));
        wf[m * 8192 + idx]        = hi;
        wf[m * 8192 + 4096 + idx] = lo;
    }
}

// ---------------- FUSED: CSR build (in LDS, never hits global) + gather +
// self-loop + bias + relu + graph-sum pool. block=(g,br), 512 thr, 142KB LDS.
// One block per CU; edge pairs come from LDS (broadcast ds_read); h is bf16
// global, XCD-local (block->XCD = g%8, both branches of g on one XCD).
__global__ __launch_bounds__(512) void csr_gcn_fused(
    const int* __restrict__ eia, const float* __restrict__ eaa,
    const int* __restrict__ eib, const float* __restrict__ eab,
    const unsigned short* __restrict__ h,
    const float* __restrict__ bga, const float* __restrict__ bgb,
    float* __restrict__ pooled) {
    extern __shared__ char smem[];
    float2* scsr = (float2*)smem;                    // 128 KB: (src, norm)
    float*  sdeg = (float*)(smem + 131072);          // 4 KB: deg -> dinv
    int*    scnt = (int*)(smem + 135168);            // 4 KB
    int*    scur = (int*)(smem + 139264);            // 4 KB (after fill: row end)
    int*    sm   = (int*)(smem + 143360);            // 2 KB scan; reused as red
    float*  red  = (float*)sm;
    const int g  = blockIdx.x;
    const int br = blockIdx.y;
    const int* ei   = br ? eib : eia;
    const float* ea = br ? eab : eaa;
    const int t     = threadIdx.x;
    const int ebase = g * EPG;
    const int nbase = g * NPG;

    for (int i = t; i < NPG; i += 512) { sdeg[i] = 0.f; scnt[i] = 0; }
    __syncthreads();

    // pass 1: weighted degree + in-degree count (LDS atomics)
#pragma unroll 4
    for (int it = 0; it < EPG / 512; ++it) {
        int e = ebase + it * 512 + t;
        int d = ei[NEDGES + e] - nbase;
        float w = ea[e];
        atomicAdd(&scnt[d], 1);
        atomicAdd(&sdeg[d], w);
    }
    __syncthreads();

    // sdeg -> dinv = rsqrt(deg+1)   (dinv^2 = 1/(deg+1) serves the self-loop)
    for (int i = t; i < NPG; i += 512) sdeg[i] = rsqrtf(sdeg[i] + 1.f);

    // block scan of scnt (2 per thread) -> scur = row start
    int c0 = scnt[t * 2 + 0], c1 = scnt[t * 2 + 1];
    int T = c0 + c1;
    sm[t] = T;
    __syncthreads();
    for (int off = 1; off < 512; off <<= 1) {
        int v = (t >= off) ? sm[t - off] : 0;
        __syncthreads();
        sm[t] += v;
        __syncthreads();
    }
    int excl = sm[t] - T;
    scur[t * 2 + 0] = excl;
    scur[t * 2 + 1] = excl + c0;
    __syncthreads();

    // pass 2: fill LDS csr via cursor atomics (after: scur[n] = row end)
#pragma unroll 4
    for (int it = 0; it < EPG / 512; ++it) {
        int e = ebase + it * 512 + t;
        int srcg = ei[e];
        int s = srcg - nbase;
        int d = ei[NEDGES + e] - nbase;
        float w = ea[e];
        int pos = atomicAdd(&scur[d], 1);
        float2 pr;
        pr.x = __int_as_float(srcg);
        pr.y = sdeg[s] * w * sdeg[d];
        scsr[pos] = pr;
    }
    __syncthreads();

    // gather + pool: wave w owns nodes [w*128, (w+1)*128)
    const unsigned short* hh = h + (size_t)br * NNODES * 64;
    const int wave = t >> 6;
    const int lane = t & 63;
    const float bias = (br ? bgb : bga)[lane];

    float psum = 0.f;
    for (int j = 0; j < 128; ++j) {
        int n = wave * 128 + j;                        // local node (wave-uniform)
        int end = __builtin_amdgcn_readfirstlane(scur[n]);
        int c   = __builtin_amdgcn_readfirstlane(scnt[n]);
        int r   = end - c;
        float s0 = 0.f, s1 = 0.f, s2 = 0.f, s3 = 0.f;
        float s4 = 0.f, s5 = 0.f, s6 = 0.f, s7 = 0.f;
        int i = 0;
        for (; i + 8 <= c; i += 8) {
            float2 p0 = scsr[r + i + 0];
            float2 p1 = scsr[r + i + 1];
            float2 p2 = scsr[r + i + 2];
            float2 p3 = scsr[r + i + 3];
            float2 p4 = scsr[r + i + 4];
            float2 p5 = scsr[r + i + 5];
            float2 p6 = scsr[r + i + 6];
            float2 p7 = scsr[r + i + 7];
            s0 = fmaf(p0.y, bf2f(hh[(size_t)__float_as_int(p0.x) * 64 + lane]), s0);
            s1 = fmaf(p1.y, bf2f(hh[(size_t)__float_as_int(p1.x) * 64 + lane]), s1);
            s2 = fmaf(p2.y, bf2f(hh[(size_t)__float_as_int(p2.x) * 64 + lane]), s2);
            s3 = fmaf(p3.y, bf2f(hh[(size_t)__float_as_int(p3.x) * 64 + lane]), s3);
            s4 = fmaf(p4.y, bf2f(hh[(size_t)__float_as_int(p4.x) * 64 + lane]), s4);
            s5 = fmaf(p5.y, bf2f(hh[(size_t)__float_as_int(p5.x) * 64 + lane]), s5);
            s6 = fmaf(p6.y, bf2f(hh[(size_t)__float_as_int(p6.x) * 64 + lane]), s6);
            s7 = fmaf(p7.y, bf2f(hh[(size_t)__float_as_int(p7.x) * 64 + lane]), s7);
        }
        for (; i + 4 <= c; i += 4) {
            float2 p0 = scsr[r + i + 0];
            float2 p1 = scsr[r + i + 1];
            float2 p2 = scsr[r + i + 2];
            float2 p3 = scsr[r + i + 3];
            s0 = fmaf(p0.y, bf2f(hh[(size_t)__float_as_int(p0.x) * 64 + lane]), s0);
            s1 = fmaf(p1.y, bf2f(hh[(size_t)__float_as_int(p1.x) * 64 + lane]), s1);
            s2 = fmaf(p2.y, bf2f(hh[(size_t)__float_as_int(p2.x) * 64 + lane]), s2);
            s3 = fmaf(p3.y, bf2f(hh[(size_t)__float_as_int(p3.x) * 64 + lane]), s3);
        }
        for (; i < c; ++i) {
            float2 p = scsr[r + i];
            s0 = fmaf(p.y, bf2f(hh[(size_t)__float_as_int(p.x) * 64 + lane]), s0);
        }
        float dinv = sdeg[n];
        float v = ((s0 + s1) + (s2 + s3)) + ((s4 + s5) + (s6 + s7))
                + bf2f(hh[(size_t)(nbase + n) * 64 + lane]) * dinv * dinv + bias;
        psum += fmaxf(v, 0.f);
    }
    red[t] = psum;
    __syncthreads();
    if (wave == 0) {
        float s = 0.f;
#pragma unroll
        for (int w2 = 0; w2 < 8; ++w2) s += red[w2 * 64 + lane];
        pooled[br * (NB * 64) + g * 64 + lane] = s;   // block owns it: no atomic
    }
}

// ---------------- fallback CSR build (static 13 KB LDS) — used if big-LDS fails
__global__ __launch_bounds__(256) void csr_build(
    const int* __restrict__ eia, const float* __restrict__ eaa,
    const int* __restrict__ eib, const float* __restrict__ eab,
    float* __restrict__ deg, int* __restrict__ rowstart,
    int* __restrict__ cnt, float2* __restrict__ csr) {
    __shared__ float sdeg[NPG];
    __shared__ int   scnt[NPG];
    __shared__ int   scur[NPG];
    __shared__ int   sm[256];
    const int g  = blockIdx.x;
    const int br = blockIdx.y;
    const int* ei   = br ? eib : eia;
    const float* ea = br ? eab : eaa;
    const int t     = threadIdx.x;
    const int ebase = g * EPG;
    const int nbase = g * NPG;

    for (int i = t; i < NPG; i += 256) { sdeg[i] = 0.f; scnt[i] = 0; }
    __syncthreads();
#pragma unroll 4
    for (int it = 0; it < EPG / 256; ++it) {
        int e = ebase + it * 256 + t;
        int d = ei[NEDGES + e] - nbase;
        float w = ea[e];
        atomicAdd(&scnt[d], 1);
        atomicAdd(&sdeg[d], w);
    }
    __syncthreads();
    for (int i = t; i < NPG; i += 256) {
        float dv = sdeg[i];
        deg[br * NNODES + nbase + i] = dv;
        sdeg[i] = rsqrtf(dv + 1.f);
    }
    int c0 = scnt[t * 4 + 0], c1 = scnt[t * 4 + 1], c2 = scnt[t * 4 + 2], c3 = scnt[t * 4 + 3];
    int T = c0 + c1 + c2 + c3;
    sm[t] = T;
    __syncthreads();
    for (int off = 1; off < 256; off <<= 1) {
        int v = (t >= off) ? sm[t - off] : 0;
        __syncthreads();
        sm[t] += v;
        __syncthreads();
    }
    int excl = sm[t] - T;
    int base = ebase + excl;
    int r0 = base, r1 = base + c0, r2 = r1 + c1, r3 = r2 + c2;
    int nout = br * NNODES + nbase + t * 4;
    rowstart[nout + 0] = r0; rowstart[nout + 1] = r1;
    rowstart[nout + 2] = r2; rowstart[nout + 3] = r3;
    cnt[nout + 0] = c0; cnt[nout + 1] = c1; cnt[nout + 2] = c2; cnt[nout + 3] = c3;
    scur[t * 4 + 0] = r0; scur[t * 4 + 1] = r1;
    scur[t * 4 + 2] = r2; scur[t * 4 + 3] = r3;
    __syncthreads();
    float2* cso = csr + (size_t)br * NEDGES;
#pragma unroll 4
    for (int it = 0; it < EPG / 256; ++it) {
        int e = ebase + it * 256 + t;
        int srcg = ei[e];
        int s = srcg - nbase;
        int d = ei[NEDGES + e] - nbase;
        float w = ea[e];
        int pos = atomicAdd(&scur[d], 1);
        float2 pr;
        pr.x = __int_as_float(srcg);
        pr.y = sdeg[s] * w * sdeg[d];
        cso[pos] = pr;
    }
}

// ---------------- MFMA node MLP: h = relu(relu(x@W1+b1)@W2+b2)@Wg -> bf16
__global__ __launch_bounds__(256) void node_mlp_mfma(
    const float* __restrict__ xa, const float* __restrict__ xb,
    const unsigned short* __restrict__ wf,
    const float* __restrict__ b1a, const float* __restrict__ b2a,
    const float* __restrict__ b1b, const float* __restrict__ b2b,
    unsigned short* __restrict__ hout) {
    __shared__ float lds[4 * 16 * 65];
    const int br = blockIdx.y;
    const float* x = br ? xb : xa;
    const unsigned short* wfb = wf + br * 3 * 8192;
    const float* b1 = br ? b1b : b1a;
    const float* b2 = br ? b2b : b2a;
    const int wave = threadIdx.x >> 6;
    const int lane = threadIdx.x & 63;
    const int row  = lane & 15;
    const int kg   = lane >> 4;
    const int n0   = blockIdx.x * 64 + wave * 16;
    float* wlds = &lds[wave * 16 * 65];

    bfrag ahi[2], alo[2];
#pragma unroll
    for (int kt = 0; kt < 2; ++kt) {
        const float4* p = reinterpret_cast<const float4*>(
            x + (size_t)(n0 + row) * 64 + kt * 32 + kg * 8);
        float4 v0 = p[0], v1 = p[1];
        float vv[8] = {v0.x, v0.y, v0.z, v0.w, v1.x, v1.y, v1.z, v1.w};
        bfrag h, l;
#pragma unroll
        for (int i = 0; i < 8; ++i) {
            unsigned short hb = f2bf(vv[i]);
            unsigned short lb = f2bf(vv[i] - bf2f(hb));
            h[i] = (short)hb;
            l[i] = (short)lb;
        }
        ahi[kt] = h; alo[kt] = l;
    }

#pragma unroll
    for (int layer = 0; layer < 3; ++layer) {
        const unsigned short* wl = wfb + layer * 8192;
        bfrag bhi[4][2], blo[4][2];
#pragma unroll
        for (int ft = 0; ft < 4; ++ft)
#pragma unroll
            for (int kt = 0; kt < 2; ++kt) {
                bhi[ft][kt] = *reinterpret_cast<const bfrag*>(wl + ft * 1024 + kt * 512 + lane * 8);
                blo[ft][kt] = *reinterpret_cast<const bfrag*>(wl + 4096 + ft * 1024 + kt * 512 + lane * 8);
            }
        f32x4 acc[4];
#pragma unroll
        for (int ft = 0; ft < 4; ++ft) {
            float bv = (layer == 0) ? b1[ft * 16 + row]
                     : (layer == 1) ? b2[ft * 16 + row] : 0.f;
            acc[ft] = (f32x4){bv, bv, bv, bv};
        }
#pragma unroll
        for (int ft = 0; ft < 4; ++ft)
#pragma unroll
            for (int kt = 0; kt < 2; ++kt) {
                acc[ft] = __builtin_amdgcn_mfma_f32_16x16x32_bf16(ahi[kt], bhi[ft][kt], acc[ft], 0, 0, 0);
                acc[ft] = __builtin_amdgcn_mfma_f32_16x16x32_bf16(alo[kt], bhi[ft][kt], acc[ft], 0, 0, 0);
                acc[ft] = __builtin_amdgcn_mfma_f32_16x16x32_bf16(ahi[kt], blo[ft][kt], acc[ft], 0, 0, 0);
            }

        if (layer < 2) {
#pragma unroll
            for (int ft = 0; ft < 4; ++ft)
#pragma unroll
                for (int r = 0; r < 4; ++r)
                    wlds[(kg * 4 + r) * 65 + ft * 16 + row] = fmaxf(acc[ft][r], 0.f);
            __syncthreads();
#pragma unroll
            for (int kt = 0; kt < 2; ++kt) {
                const float* rp = &wlds[row * 65 + kt * 32 + kg * 8];
                bfrag h, l;
#pragma unroll
                for (int i = 0; i < 8; ++i) {
                    float v = rp[i];
                    unsigned short hb = f2bf(v);
                    unsigned short lb = f2bf(v - bf2f(hb));
                    h[i] = (short)hb;
                    l[i] = (short)lb;
                }
                ahi[kt] = h; alo[kt] = l;
            }
            __syncthreads();
        } else {
            unsigned short* hp = hout + (size_t)br * NNODES * 64 + (size_t)n0 * 64;
#pragma unroll
            for (int ft = 0; ft < 4; ++ft)
#pragma unroll
                for (int r = 0; r < 4; ++r)
                    hp[(kg * 4 + r) * 64 + ft * 16 + row] = f2bf(acc[ft][r]);
        }
    }
}

// ---------------- fallback gather (round-8 version, bf16 h)
__global__ __launch_bounds__(256) void gcn_gather_pool(
    const int* __restrict__ rowstart, const int* __restrict__ cnt,
    const float2* __restrict__ csr, const float* __restrict__ deg,
    const unsigned short* __restrict__ h,
    const float* __restrict__ bga, const float* __restrict__ bgb,
    float* __restrict__ pooled) {
    __shared__ float red[256];
    const int bid  = blockIdx.x;
    const int xcd  = bid & 7;
    const int sub  = bid >> 3;
    const int gb   = xcd * 32 + (sub >> 4);
    const int blk  = sub & 15;
    const int br   = gb >> 7;
    const int g    = gb & 127;
    const int wave = threadIdx.x >> 6;
    const int lane = threadIdx.x & 63;
    const int n0   = g * NPG + blk * 64 + wave * 16;

    const int*    rs = rowstart + br * NNODES;
    const int*    ct = cnt + br * NNODES;
    const float2* cs = csr + (size_t)br * NEDGES;
    const float*  dg = deg + br * NNODES;
    const unsigned short* hh = h + (size_t)br * NNODES * 64;
    const float bias = (br ? bgb : bga)[lane];

    float psum = 0.f;
    for (int j = 0; j < 16; ++j) {
        int n = n0 + j;
        int r = __builtin_amdgcn_readfirstlane(rs[n]);
        int c = __builtin_amdgcn_readfirstlane(ct[n]);
        float s0 = 0.f, s1 = 0.f, s2 = 0.f, s3 = 0.f;
        int i = 0;
        for (; i + 4 <= c; i += 4) {
            float2 p0 = cs[r + i + 0];
            float2 p1 = cs[r + i + 1];
            float2 p2 = cs[r + i + 2];
            float2 p3 = cs[r + i + 3];
            s0 = fmaf(p0.y, bf2f(hh[(size_t)__float_as_int(p0.x) * 64 + lane]), s0);
            s1 = fmaf(p1.y, bf2f(hh[(size_t)__float_as_int(p1.x) * 64 + lane]), s1);
            s2 = fmaf(p2.y, bf2f(hh[(size_t)__float_as_int(p2.x) * 64 + lane]), s2);
            s3 = fmaf(p3.y, bf2f(hh[(size_t)__float_as_int(p3.x) * 64 + lane]), s3);
        }
        for (; i < c; ++i) {
            float2 p = cs[r + i];
            s0 = fmaf(p.y, bf2f(hh[(size_t)__float_as_int(p.x) * 64 + lane]), s0);
        }
        float d = dg[n] + 1.f;
        float v = (s0 + s1) + (s2 + s3)
                + bf2f(hh[(size_t)n * 64 + lane]) * (1.f / d) + bias;
        psum += fmaxf(v, 0.f);
    }
    red[threadIdx.x] = psum;
    __syncthreads();
    if (wave == 0) {
        float s = red[lane] + red[64 + lane] + red[128 + lane] + red[192 + lane];
        unsafeAtomicAdd(&pooled[br * (NB * 64) + g * 64 + lane], s);
    }
}

// ---------------- final MLP heads
__global__ __launch_bounds__(128) void final_mlp(
    const float* __restrict__ pooled, const float* __restrict__ linker,
    const float* __restrict__ W1, const float* __restrict__ b1,
    const float* __restrict__ W2, const float* __restrict__ b2,
    const float* __restrict__ W3, const float* __restrict__ b3,
    const float* __restrict__ Wcb, const float* __restrict__ bcb,
    const float* __restrict__ Wom, const float* __restrict__ bom,
    const float* __restrict__ Wth, const float* __restrict__ bth,
    const float* __restrict__ Wph, const float* __restrict__ bph,
    float* __restrict__ out) {
    __shared__ float inv[260];
    __shared__ float x1[128];
    __shared__ float x2[64];
    const int g = blockIdx.x;
    const int t = threadIdx.x;
    if (t < 64) {
        float pa = pooled[g * 64 + t];
        float pb = pooled[NB * 64 + g * 64 + t];
        inv[t]       = pa;
        inv[64 + t]  = pa * (1.f / 1024.f);
        inv[128 + t] = pb;
        inv[192 + t] = pb * (1.f / 1024.f);
    }
    if (t == 0) inv[256] = linker[g];
    __syncthreads();

    {
        float a = b1[t];
        for (int i = 0; i < 257; ++i) a = fmaf(inv[i], W1[i * 128 + t], a);
        x1[t] = fmaxf(a, 0.f);
    }
    __syncthreads();
    if (t < 64) {
        float a = b2[t];
        for (int i = 0; i < 128; ++i) a = fmaf(x1[i], W2[i * 64 + t], a);
        x2[t] = fmaxf(a, 0.f);
    }
    __syncthreads();
    if (t < 8) {
        if (t == 0) {
            float a = b3[0];
            for (int i = 0; i < 64; ++i) a = fmaf(x2[i], W3[i], a);
            out[g] = a;
        } else if (t == 1) {
            float a = bcb[0];
            for (int i = 0; i < 64; ++i) a = fmaf(x2[i], Wcb[i], a);
            out[128 + g] = a;
        } else if (t < 4) {
            int j = t - 2; float a = bom[j];
            for (int i = 0; i < 64; ++i) a = fmaf(x2[i], Wom[i * 2 + j], a);
            out[256 + g * 2 + j] = a;
        } else if (t < 6) {
            int j = t - 4; float a = bth[j];
            for (int i = 0; i < 64; ++i) a = fmaf(x2[i], Wth[i * 2 + j], a);
            out[512 + g * 2 + j] = a;
        } else {
            int j = t - 6; float a = bph[j];
            for (int i = 0; i < 64; ++i) a = fmaf(x2[i], Wph[i * 2 + j], a);
            out[768 + g * 2 + j] = a;
        }
    }
}

extern "C" void kernel_launch(void* const* d_in, const int* in_sizes, int n_in,
                              void* d_out, int out_size, void* d_ws, size_t ws_size,
                              hipStream_t stream) {
    const float* x_a  = (const float*)d_in[0];
    const int*   ei_a = (const int*)d_in[1];
    const float* ea_a = (const float*)d_in[2];
    const float* x_b  = (const float*)d_in[4];
    const int*   ei_b = (const int*)d_in[5];
    const float* ea_b = (const float*)d_in[6];
    const float* linker = (const float*)d_in[8];
    const float* W_pre1_a = (const float*)d_in[9];
    const float* b_pre1_a = (const float*)d_in[10];
    const float* W_pre2_a = (const float*)d_in[11];
    const float* b_pre2_a = (const float*)d_in[12];
    const float* W_gcn_a  = (const float*)d_in[13];
    const float* b_gcn_a  = (const float*)d_in[14];
    const float* W_pre1_b = (const float*)d_in[15];
    const float* b_pre1_b = (const float*)d_in[16];
    const float* W_pre2_b = (const float*)d_in[17];
    const float* b_pre2_b = (const float*)d_in[18];
    const float* W_gcn_b  = (const float*)d_in[19];
    const float* b_gcn_b  = (const float*)d_in[20];
    const float* W_lin1 = (const float*)d_in[21];
    const float* b_lin1 = (const float*)d_in[22];
    const float* W_lin2 = (const float*)d_in[23];
    const float* b_lin2 = (const float*)d_in[24];
    const float* W_lin3 = (const float*)d_in[25];
    const float* b_lin3 = (const float*)d_in[26];
    const float* W_cb = (const float*)d_in[27];
    const float* b_cb = (const float*)d_in[28];
    const float* W_om = (const float*)d_in[29];
    const float* b_om = (const float*)d_in[30];
    const float* W_th = (const float*)d_in[31];
    const float* b_th = (const float*)d_in[32];
    const float* W_ph = (const float*)d_in[33];
    const float* b_ph = (const float*)d_in[34];

    float* ws     = (float*)d_ws;
    float* deg    = ws + OFF_DEG;
    float* pooled = ws + OFF_POOLED;
    float* wtw    = ws + OFF_WT;
    unsigned short* h = (unsigned short*)(ws + OFF_H);
    int*   cnt      = (int*)(ws + OFF_CNT);
    int*   rowstart = (int*)(ws + OFF_ROWSTART);
    float2* csr     = (float2*)(ws + OFF_CSR);

    wprep<<<6, 256, 0, stream>>>(W_pre1_a, W_pre2_a, W_gcn_a,
                                 W_pre1_b, W_pre2_b, W_gcn_b,
                                 (unsigned short*)wtw);
    node_mlp_mfma<<<dim3(NNODES / 64, 2), 256, 0, stream>>>(
        x_a, x_b, (const unsigned short*)wtw,
        b_pre1_a, b_pre2_a, b_pre1_b, b_pre2_b, h);

    hipError_t attr_ok = hipFuncSetAttribute(
        reinterpret_cast<const void*>(&csr_gcn_fused),
        hipFuncAttributeMaxDynamicSharedMemorySize, FUSE_LDS);
    if (attr_ok == hipSuccess) {
        csr_gcn_fused<<<dim3(NB, 2), 512, FUSE_LDS, stream>>>(
            ei_a, ea_a, ei_b, ea_b, h, b_gcn_a, b_gcn_b, pooled);
    } else {
        hipMemsetAsync(pooled, 0, 2 * NB * 64 * sizeof(float), stream);
        csr_build<<<dim3(NB, 2), 256, 0, stream>>>(ei_a, ea_a, ei_b, ea_b,
                                                   deg, rowstart, cnt, csr);
        gcn_gather_pool<<<4096, 256, 0, stream>>>(rowstart, cnt, csr, deg, h,
                                                  b_gcn_a, b_gcn_b, pooled);
    }

    final_mlp<<<NB, 128, 0, stream>>>(pooled, linker,
                                      W_lin1, b_lin1, W_lin2, b_lin2, W_lin3, b_lin3,
                                      W_cb, b_cb, W_om, b_om, W_th, b_th, W_ph, b_ph,
                                      (float*)d_out);
}